// Round 4
// baseline (185.187 us; speedup 1.0000x reference)
//
#include <hip/hip_runtime.h>

#define BB 4
#define CC 64
#define OO 64
#define HH 128
#define WW 128
#define HP 131          // padded rows (0..130 valid)
#define WP 132          // padded row width
#define HW (HH*WW)
#define OFFSTR 20       // floats per pixel in offs buffer (tap*2 + {h,w})

typedef __attribute__((ext_vector_type(8))) short short8;
typedef __attribute__((ext_vector_type(4))) float f32x4;

__device__ __forceinline__ unsigned f2b(float f) {  // RNE float->bf16 bits
  unsigned u = __float_as_uint(f);
  return (u + 0x7fffu + ((u >> 16) & 1u)) >> 16;
}
__device__ __forceinline__ float blo(unsigned r) { return __uint_as_float(r << 16); }
__device__ __forceinline__ float bhi(unsigned r) { return __uint_as_float(r & 0xffff0000u); }
__device__ __forceinline__ unsigned pk2(float a, float b) { return f2b(a) | (f2b(b) << 16); }

// ---------------- pad + bf16 + CHANNEL-LAST: xp[b][hp][wp][c2] (uint = ch pair 2c2,2c2+1) ----------------
__global__ __launch_bounds__(256) void pad_kernel(const float* __restrict__ x,
                                                  unsigned* __restrict__ xp) {
  int i = blockIdx.x * 256 + threadIdx.x;       // (b,hp,wp,c8): c8 = 8-channel chunk
  if (i >= BB * HP * WP * 8) return;
  int c8 = i & 7;
  int t = i >> 3;                                // (b,hp,wp)
  int wp = t % WP;
  int t2 = t / WP;
  int hp = t2 % HP;
  int b = t2 / HP;
  uint4 v = make_uint4(0, 0, 0, 0);
  if (hp >= 1 && hp <= HH && wp >= 1 && wp <= WW) {
    const float* s = x + (((size_t)(b * CC + c8 * 8)) * HH + (hp - 1)) * WW + (wp - 1);
    v.x = pk2(s[0], s[HW]);
    v.y = pk2(s[2 * HW], s[3 * HW]);
    v.z = pk2(s[4 * HW], s[5 * HW]);
    v.w = pk2(s[6 * HW], s[7 * HW]);
  }
  *(uint4*)(xp + (size_t)t * 32 + c8 * 4) = v;
}

// ---------------- weight repack to bf16, K-index = kk*64+c ----------------
__global__ __launch_bounds__(256) void repackw_kernel(const float* __restrict__ wt,
                                                      const float* __restrict__ ow,
                                                      ushort* __restrict__ wb,
                                                      ushort* __restrict__ owb) {
  int i = blockIdx.x * 256 + threadIdx.x;
  if (i < OO * 576) {
    int o = i / 576, r = i % 576;
    int kk = r >> 6, c = r & 63;
    wb[i] = (ushort)f2b(wt[(o * CC + c) * 9 + kk]);
  } else if (i < OO * 576 + 32 * 576) {
    int j = i - OO * 576;
    int oc = j / 576, r = j % 576;
    int kk = r >> 6, c = r & 63;
    owb[j] = (oc < 18) ? (ushort)f2b(ow[(oc * CC + c) * 9 + kk]) : (ushort)0;
  }
}

// ---------------- offset conv: register-direct MFMA, K-split, no lerp ----------------
// wave (g,s): g=pixel group (16 px), s=channel half; 2048 blocks x 4 waves
__global__ __launch_bounds__(256, 8) void offs_gemm(const unsigned* __restrict__ xp,
                                                    const ushort* __restrict__ owb,
                                                    const float* __restrict__ ob,
                                                    float* __restrict__ offs) {
  __shared__ float red[2 * 16 * 36];
  int tid = threadIdx.x;
  int blk0 = blockIdx.x;
  int blk = (blk0 & 7) * 256 + (blk0 >> 3);     // XCD-slab swizzle
  int wave = tid >> 6, lane = tid & 63, lm = lane & 15, lq = lane >> 4;
  int g = wave & 1, s = wave >> 1;
  int base = blk * 32 + g * 16;
  int b = base >> 14, h = (base >> 7) & 127, wt = base & 127;
  int w = wt + lm;

  f32x4 acc[2];
  acc[0] = (f32x4)0.0f; acc[1] = (f32x4)0.0f;
  const unsigned* xb = xp + (size_t)b * (HP * WP * 32);
  int cbase = s * 16 + lq * 4;

#pragma unroll 1
  for (int kh = 0; kh < 3; ++kh) {
#pragma unroll
    for (int kw = 0; kw < 3; ++kw) {
      int kk = kh * 3 + kw;
      union { uint4 q; short8 v; } a;
      a.q = *(const uint4*)(xb + ((size_t)(h + kh) * WP + (w + kw)) * 32 + cbase);
#pragma unroll
      for (int nt = 0; nt < 2; ++nt) {
        short8 bf = *(const short8*)&owb[(size_t)(nt * 16 + lm) * 576 + kk * 64 + s * 32 + lq * 8];
        acc[nt] = __builtin_amdgcn_mfma_f32_16x16x32_bf16(a.v, bf, acc[nt], 0, 0, 0);
      }
    }
  }
  if (s == 1) {
#pragma unroll
    for (int nt = 0; nt < 2; ++nt)
#pragma unroll
      for (int r = 0; r < 4; ++r)
        red[g * 576 + (lq * 4 + r) * 36 + nt * 16 + lm] = acc[nt][r];
  }
  __syncthreads();
  if (s == 0) {
#pragma unroll
    for (int nt = 0; nt < 2; ++nt) {
      int oc = nt * 16 + lm;
      if (oc < 18) {
        float bv = ob[oc];
        int idx = (oc < 9) ? (oc * 2) : ((oc - 9) * 2 + 1);
#pragma unroll
        for (int r = 0; r < 4; ++r) {
          int pix = base + lq * 4 + r;
          offs[(size_t)pix * OFFSTR + idx] = acc[nt][r] + red[g * 576 + (lq * 4 + r) * 36 + oc] + bv;
        }
      }
    }
  }
}

// ---------------- deformable conv: register-direct MFMA, K-split bilinear gather ----------------
__global__ __launch_bounds__(256, 6) void deform_gemm(const unsigned* __restrict__ xp,
                                                      const ushort* __restrict__ wb,
                                                      const float* __restrict__ bias,
                                                      const float* __restrict__ offs,
                                                      float* __restrict__ out) {
  __shared__ float red[2 * 16 * 68];
  int tid = threadIdx.x;
  int blk0 = blockIdx.x;
  int blk = (blk0 & 7) * 256 + (blk0 >> 3);     // XCD-slab swizzle
  int wave = tid >> 6, lane = tid & 63, lm = lane & 15, lq = lane >> 4;
  int g = wave & 1, s = wave >> 1;
  int base = blk * 32 + g * 16;
  int b = base >> 14, h = (base >> 7) & 127, wt = base & 127;
  int w = wt + lm;
  int pix = base + lm;

  f32x4 acc[4];
#pragma unroll
  for (int nt = 0; nt < 4; ++nt) acc[nt] = (f32x4)0.0f;

  const unsigned* xb = xp + (size_t)b * (HP * WP * 32);
  const float* op = offs + (size_t)pix * OFFSTR;
  int cbase = s * 16 + lq * 4;

#pragma unroll 1
  for (int kh = 0; kh < 3; ++kh) {
#pragma unroll 1
    for (int kw = 0; kw < 3; ++kw) {
      int kk = kh * 3 + kw;
      float2 off = *(const float2*)(op + kk * 2);
      // padded coords, mirror reference op order; clip to [0, Hp-1]=129
      float ph = (((float)kh + off.x) + (float)h) + 1.0f;
      float pw = (((float)kw + off.y) + (float)w) + 1.0f;
      ph = fminf(fmaxf(ph, 0.0f), 129.0f);
      pw = fminf(fmaxf(pw, 0.0f), 129.0f);
      float fh0 = floorf(ph), fw0 = floorf(pw);
      int h0 = (int)fh0, w0 = (int)fw0;          // 0..129; +1 row/col stays in-bounds
      float wh1 = ph - fh0, ww1 = pw - fw0;
      float wh0 = 1.0f - wh1, ww0 = 1.0f - ww1;

      const unsigned* p00 = xb + ((size_t)h0 * WP + w0) * 32 + cbase;
      uint4 q00 = *(const uint4*)p00;
      uint4 q01 = *(const uint4*)(p00 + 32);
      uint4 q10 = *(const uint4*)(p00 + WP * 32);
      uint4 q11 = *(const uint4*)(p00 + WP * 32 + 32);
      unsigned A00[4] = {q00.x, q00.y, q00.z, q00.w};
      unsigned A01[4] = {q01.x, q01.y, q01.z, q01.w};
      unsigned A10[4] = {q10.x, q10.y, q10.z, q10.w};
      unsigned A11[4] = {q11.x, q11.y, q11.z, q11.w};

      union { unsigned u[4]; short8 v; } a;
#pragma unroll
      for (int t = 0; t < 4; ++t) {
        float topL = fmaf(blo(A01[t]), ww1, blo(A00[t]) * ww0);
        float botL = fmaf(blo(A11[t]), ww1, blo(A10[t]) * ww0);
        float vL = fmaf(botL, wh1, topL * wh0);
        float topH = fmaf(bhi(A01[t]), ww1, bhi(A00[t]) * ww0);
        float botH = fmaf(bhi(A11[t]), ww1, bhi(A10[t]) * ww0);
        float vH = fmaf(botH, wh1, topH * wh0);
        a.u[t] = pk2(vL, vH);
      }
#pragma unroll
      for (int nt = 0; nt < 4; ++nt) {
        short8 bf = *(const short8*)&wb[(size_t)(nt * 16 + lm) * 576 + kk * 64 + s * 32 + lq * 8];
        acc[nt] = __builtin_amdgcn_mfma_f32_16x16x32_bf16(a.v, bf, acc[nt], 0, 0, 0);
      }
    }
  }

  if (s == 1) {
#pragma unroll
    for (int nt = 0; nt < 4; ++nt)
#pragma unroll
      for (int r = 0; r < 4; ++r)
        red[g * 1088 + (lq * 4 + r) * 68 + nt * 16 + lm] = acc[nt][r];
  }
  __syncthreads();
  if (s == 0) {
#pragma unroll
    for (int nt = 0; nt < 4; ++nt) {
      int o = nt * 16 + lm;
      float bv = bias[o];
      float4 st;
      st.x = acc[nt][0] + red[g * 1088 + (lq * 4 + 0) * 68 + o] + bv;
      st.y = acc[nt][1] + red[g * 1088 + (lq * 4 + 1) * 68 + o] + bv;
      st.z = acc[nt][2] + red[g * 1088 + (lq * 4 + 2) * 68 + o] + bv;
      st.w = acc[nt][3] + red[g * 1088 + (lq * 4 + 3) * 68 + o] + bv;
      *(float4*)(out + ((size_t)(b * OO + o) * HH + h) * WW + wt + lq * 4) = st;
    }
  }
}

extern "C" void kernel_launch(void* const* d_in, const int* in_sizes, int n_in,
                              void* d_out, int out_size, void* d_ws, size_t ws_size,
                              hipStream_t stream) {
  const float* x        = (const float*)d_in[0];
  const float* weight   = (const float*)d_in[1];
  const float* bias     = (const float*)d_in[2];
  const float* offset_w = (const float*)d_in[3];
  const float* offset_b = (const float*)d_in[4];
  float* out = (float*)d_out;

  // ws layout
  unsigned* xp  = (unsigned*)d_ws;                         // 4*131*132*32 uints = 8.85 MB
  ushort* wb  = (ushort*)(xp + (size_t)BB * HP * WP * 32); // 64*576
  ushort* owb = wb + (size_t)OO * 576;                     // 32*576
  float* offs = (float*)(owb + (size_t)32 * 576);          // 65536*20 floats

  pad_kernel<<<(BB * HP * WP * 8 + 255) / 256, 256, 0, stream>>>(x, xp);
  repackw_kernel<<<(OO * 576 + 32 * 576 + 255) / 256, 256, 0, stream>>>(weight, offset_w, wb, owb);
  offs_gemm<<<2048, 256, 0, stream>>>(xp, owb, offset_b, offs);
  deform_gemm<<<2048, 256, 0, stream>>>(xp, wb, bias, offs, out);
}

// Round 5
// 173.992 us; speedup vs baseline: 1.0643x; 1.0643x over previous
//
#include <hip/hip_runtime.h>

#define BB 4
#define CC 64
#define OO 64
#define HH 128
#define WW 128
#define HP 131          // padded rows (0..130 valid)
#define WP 132          // padded row width
#define HW (HH*WW)
#define OFFSTR 20       // floats per pixel in offs buffer: [tap*2 + {h:0,w:1}], 2 pad

typedef __attribute__((ext_vector_type(8))) short short8;
typedef __attribute__((ext_vector_type(4))) float f32x4;

__device__ __forceinline__ unsigned f2b(float f) {  // RNE float->bf16 bits
  unsigned u = __float_as_uint(f);
  return (u + 0x7fffu + ((u >> 16) & 1u)) >> 16;
}
__device__ __forceinline__ float blo(unsigned r) { return __uint_as_float(r << 16); }
__device__ __forceinline__ float bhi(unsigned r) { return __uint_as_float(r & 0xffff0000u); }
__device__ __forceinline__ unsigned pk2(float a, float b) { return f2b(a) | (f2b(b) << 16); }

// ---------------- pad + bf16 + CHANNEL-LAST: xp[b][hp][wp][c2] (uint = ch pair) ----------------
__global__ __launch_bounds__(256) void pad_kernel(const float* __restrict__ x,
                                                  unsigned* __restrict__ xp) {
  int i = blockIdx.x * 256 + threadIdx.x;       // (b,hp,wp,c8)
  if (i >= BB * HP * WP * 8) return;
  int c8 = i & 7;
  int t = i >> 3;
  int wp = t % WP;
  int t2 = t / WP;
  int hp = t2 % HP;
  int b = t2 / HP;
  uint4 v = make_uint4(0, 0, 0, 0);
  if (hp >= 1 && hp <= HH && wp >= 1 && wp <= WW) {
    const float* s = x + (((size_t)(b * CC + c8 * 8)) * HH + (hp - 1)) * WW + (wp - 1);
    v.x = pk2(s[0], s[HW]);
    v.y = pk2(s[2 * HW], s[3 * HW]);
    v.z = pk2(s[4 * HW], s[5 * HW]);
    v.w = pk2(s[6 * HW], s[7 * HW]);
  }
  *(uint4*)(xp + (size_t)t * 32 + c8 * 4) = v;
}

// ---------------- weight repack to bf16, K-index = kk*64+c ----------------
__global__ __launch_bounds__(256) void repackw_kernel(const float* __restrict__ wt,
                                                      const float* __restrict__ ow,
                                                      ushort* __restrict__ wb,
                                                      ushort* __restrict__ owb) {
  int i = blockIdx.x * 256 + threadIdx.x;
  if (i < OO * 576) {
    int o = i / 576, r = i % 576;
    int kk = r >> 6, c = r & 63;
    wb[i] = (ushort)f2b(wt[(o * CC + c) * 9 + kk]);
  } else if (i < OO * 576 + 32 * 576) {
    int j = i - OO * 576;
    int oc = j / 576, r = j % 576;
    int kk = r >> 6, c = r & 63;
    owb[j] = (oc < 18) ? (ushort)f2b(ow[(oc * CC + c) * 9 + kk]) : (ushort)0;
  }
}

// ---------------- offset conv: register-direct MFMA, full K per wave, fully unrolled ----------------
// wave = 16 px, N=32 (18 valid), K=576; 1024 blocks x 4 waves
__global__ __launch_bounds__(256, 4) void offs_gemm(const unsigned* __restrict__ xp,
                                                    const ushort* __restrict__ owb,
                                                    const float* __restrict__ ob,
                                                    float* __restrict__ offs) {
  int tid = threadIdx.x;
  int blk0 = blockIdx.x;
  int blk = (blk0 & 7) * 128 + (blk0 >> 3);     // XCD-slab swizzle (8 slabs)
  int wave = tid >> 6, lane = tid & 63, lm = lane & 15, lq = lane >> 4;
  int base = blk * 64 + wave * 16;
  int b = base >> 14, h = (base >> 7) & 127, wt = base & 127;
  int w = wt + lm;

  f32x4 acc[2];
  acc[0] = (f32x4)0.0f; acc[1] = (f32x4)0.0f;
  const unsigned* xb = xp + (size_t)b * (HP * WP * 32);

#pragma unroll
  for (int kk = 0; kk < 9; ++kk) {
    int kh = kk / 3, kw = kk % 3;
    const unsigned* p0 = xb + ((size_t)(h + kh) * WP + (w + kw)) * 32 + lq * 4;
    union { uint4 q; short8 v; } a0, a1;
    a0.q = *(const uint4*)p0;            // s=0: channels lq*8..+7
    a1.q = *(const uint4*)(p0 + 16);     // s=1: channels 32+lq*8..+7
#pragma unroll
    for (int nt = 0; nt < 2; ++nt) {
      short8 b0 = *(const short8*)&owb[(size_t)(nt * 16 + lm) * 576 + kk * 64 + lq * 8];
      short8 b1 = *(const short8*)&owb[(size_t)(nt * 16 + lm) * 576 + kk * 64 + 32 + lq * 8];
      acc[nt] = __builtin_amdgcn_mfma_f32_16x16x32_bf16(a0.v, b0, acc[nt], 0, 0, 0);
      acc[nt] = __builtin_amdgcn_mfma_f32_16x16x32_bf16(a1.v, b1, acc[nt], 0, 0, 0);
    }
  }
#pragma unroll
  for (int nt = 0; nt < 2; ++nt) {
    int oc = nt * 16 + lm;
    if (oc < 18) {
      float bv = ob[oc];
      int idx = (oc < 9) ? (oc * 2) : ((oc - 9) * 2 + 1);
#pragma unroll
      for (int r = 0; r < 4; ++r) {
        int pix = base + lq * 4 + r;
        offs[(size_t)pix * OFFSTR + idx] = acc[nt][r] + bv;
      }
    }
  }
}

// ---------------- deformable conv: register-direct MFMA, full K per wave, fully unrolled ----------------
__global__ __launch_bounds__(256, 4) void deform_gemm(const unsigned* __restrict__ xp,
                                                      const ushort* __restrict__ wb,
                                                      const float* __restrict__ bias,
                                                      const float* __restrict__ offs,
                                                      float* __restrict__ out) {
  int tid = threadIdx.x;
  int blk0 = blockIdx.x;
  int blk = (blk0 & 7) * 128 + (blk0 >> 3);     // XCD-slab swizzle
  int wave = tid >> 6, lane = tid & 63, lm = lane & 15, lq = lane >> 4;
  int base = blk * 64 + wave * 16;
  int b = base >> 14, h = (base >> 7) & 127, wt = base & 127;
  int w = wt + lm;
  int pix = base + lm;

  f32x4 acc[4];
#pragma unroll
  for (int nt = 0; nt < 4; ++nt) acc[nt] = (f32x4)0.0f;

  const unsigned* xb = xp + (size_t)b * (HP * WP * 32);

  // preload this pixel's 18 offsets (16B-aligned 80B row)
  float orow[OFFSTR];
  {
    const float* orp = offs + (size_t)pix * OFFSTR;
#pragma unroll
    for (int q = 0; q < 5; ++q) *(float4*)&orow[q * 4] = *(const float4*)(orp + q * 4);
  }

#pragma unroll
  for (int kk = 0; kk < 9; ++kk) {
    int kh = kk / 3, kw = kk % 3;
    // padded coords, mirror reference op order; clip to [0, Hp-1]=129
    float ph = (((float)kh + orow[kk * 2]) + (float)h) + 1.0f;
    float pw = (((float)kw + orow[kk * 2 + 1]) + (float)w) + 1.0f;
    ph = fminf(fmaxf(ph, 0.0f), 129.0f);
    pw = fminf(fmaxf(pw, 0.0f), 129.0f);
    float fh0 = floorf(ph), fw0 = floorf(pw);
    int h0 = (int)fh0, w0 = (int)fw0;            // 0..129; +1 row/col stays in padded bounds
    float wh1 = ph - fh0, ww1 = pw - fw0;
    float wh0 = 1.0f - wh1, ww0 = 1.0f - ww1;

    const unsigned* p00 = xb + ((size_t)h0 * WP + w0) * 32 + lq * 4;
    // 8 independent 16B gathers (4 corners x 2 K-halves) — issue all, then lerp
    uint4 q00a = *(const uint4*)p00;
    uint4 q01a = *(const uint4*)(p00 + 32);
    uint4 q10a = *(const uint4*)(p00 + WP * 32);
    uint4 q11a = *(const uint4*)(p00 + WP * 32 + 32);
    uint4 q00b = *(const uint4*)(p00 + 16);
    uint4 q01b = *(const uint4*)(p00 + 48);
    uint4 q10b = *(const uint4*)(p00 + WP * 32 + 16);
    uint4 q11b = *(const uint4*)(p00 + WP * 32 + 48);

    union { unsigned u[4]; short8 v; } A0, A1;
    {
      unsigned c00[4] = {q00a.x, q00a.y, q00a.z, q00a.w};
      unsigned c01[4] = {q01a.x, q01a.y, q01a.z, q01a.w};
      unsigned c10[4] = {q10a.x, q10a.y, q10a.z, q10a.w};
      unsigned c11[4] = {q11a.x, q11a.y, q11a.z, q11a.w};
#pragma unroll
      for (int t = 0; t < 4; ++t) {
        float tL = fmaf(blo(c01[t]), ww1, blo(c00[t]) * ww0);
        float bL = fmaf(blo(c11[t]), ww1, blo(c10[t]) * ww0);
        float tH = fmaf(bhi(c01[t]), ww1, bhi(c00[t]) * ww0);
        float bH = fmaf(bhi(c11[t]), ww1, bhi(c10[t]) * ww0);
        A0.u[t] = pk2(fmaf(bL, wh1, tL * wh0), fmaf(bH, wh1, tH * wh0));
      }
    }
    {
      unsigned c00[4] = {q00b.x, q00b.y, q00b.z, q00b.w};
      unsigned c01[4] = {q01b.x, q01b.y, q01b.z, q01b.w};
      unsigned c10[4] = {q10b.x, q10b.y, q10b.z, q10b.w};
      unsigned c11[4] = {q11b.x, q11b.y, q11b.z, q11b.w};
#pragma unroll
      for (int t = 0; t < 4; ++t) {
        float tL = fmaf(blo(c01[t]), ww1, blo(c00[t]) * ww0);
        float bL = fmaf(blo(c11[t]), ww1, blo(c10[t]) * ww0);
        float tH = fmaf(bhi(c01[t]), ww1, bhi(c00[t]) * ww0);
        float bH = fmaf(bhi(c11[t]), ww1, bhi(c10[t]) * ww0);
        A1.u[t] = pk2(fmaf(bL, wh1, tL * wh0), fmaf(bH, wh1, tH * wh0));
      }
    }
#pragma unroll
    for (int nt = 0; nt < 4; ++nt) {
      short8 b0 = *(const short8*)&wb[(size_t)(nt * 16 + lm) * 576 + kk * 64 + lq * 8];
      short8 b1 = *(const short8*)&wb[(size_t)(nt * 16 + lm) * 576 + kk * 64 + 32 + lq * 8];
      acc[nt] = __builtin_amdgcn_mfma_f32_16x16x32_bf16(A0.v, b0, acc[nt], 0, 0, 0);
      acc[nt] = __builtin_amdgcn_mfma_f32_16x16x32_bf16(A1.v, b1, acc[nt], 0, 0, 0);
    }
  }

  // epilogue: o = nt*16+lm; D rows lq*4+r are 4 consecutive w -> float4 store
#pragma unroll
  for (int nt = 0; nt < 4; ++nt) {
    int o = nt * 16 + lm;
    float bv = bias[o];
    float4 st = make_float4(acc[nt][0] + bv, acc[nt][1] + bv, acc[nt][2] + bv, acc[nt][3] + bv);
    *(float4*)(out + ((size_t)(b * OO + o) * HH + h) * WW + wt + lq * 4) = st;
  }
}

extern "C" void kernel_launch(void* const* d_in, const int* in_sizes, int n_in,
                              void* d_out, int out_size, void* d_ws, size_t ws_size,
                              hipStream_t stream) {
  const float* x        = (const float*)d_in[0];
  const float* weight   = (const float*)d_in[1];
  const float* bias     = (const float*)d_in[2];
  const float* offset_w = (const float*)d_in[3];
  const float* offset_b = (const float*)d_in[4];
  float* out = (float*)d_out;

  // ws layout
  unsigned* xp  = (unsigned*)d_ws;                         // 4*131*132*32 uints = 8.85 MB
  ushort* wb  = (ushort*)(xp + (size_t)BB * HP * WP * 32); // 64*576
  ushort* owb = wb + (size_t)OO * 576;                     // 32*576
  float* offs = (float*)(owb + (size_t)32 * 576);          // 65536*20 floats

  pad_kernel<<<(BB * HP * WP * 8 + 255) / 256, 256, 0, stream>>>(x, xp);
  repackw_kernel<<<(OO * 576 + 32 * 576 + 255) / 256, 256, 0, stream>>>(weight, offset_w, wb, owb);
  offs_gemm<<<1024, 256, 0, stream>>>(xp, owb, offset_b, offs);
  deform_gemm<<<1024, 256, 0, stream>>>(xp, wb, bias, offs, out);
}

// Round 6
// 136.564 us; speedup vs baseline: 1.3560x; 1.2741x over previous
//
#include <hip/hip_runtime.h>

#define BB 4
#define CC 64
#define OO 64
#define HH 128
#define WW 128
#define HP 131          // padded rows (0..130 valid)
#define WP 132          // padded row width
#define HW (HH*WW)

#define TH 8            // output tile rows per block
#define TW 8            // output tile cols per block
#define WR 15           // staged window rows (tile + 3x3 reach + ~±2 offset margin)
#define WC 15           // staged window cols
#define NWIN (WR*WC)    // 225 pixels
#define PXS 36          // LDS dwords per window pixel (32 ch-pairs + 4 pad for bank spread)

typedef __attribute__((ext_vector_type(8))) short short8;
typedef __attribute__((ext_vector_type(4))) float f32x4;

__device__ __forceinline__ unsigned f2b(float f) {  // RNE float->bf16 bits
  unsigned u = __float_as_uint(f);
  return (u + 0x7fffu + ((u >> 16) & 1u)) >> 16;
}
__device__ __forceinline__ float blo(unsigned r) { return __uint_as_float(r << 16); }
__device__ __forceinline__ float bhi(unsigned r) { return __uint_as_float(r & 0xffff0000u); }
__device__ __forceinline__ unsigned pk2(float a, float b) { return f2b(a) | (f2b(b) << 16); }

__device__ __forceinline__ short8 lerp8(uint4 q00, uint4 q01, uint4 q10, uint4 q11,
                                        float ww0, float ww1, float wh0, float wh1) {
  unsigned c00[4] = {q00.x, q00.y, q00.z, q00.w};
  unsigned c01[4] = {q01.x, q01.y, q01.z, q01.w};
  unsigned c10[4] = {q10.x, q10.y, q10.z, q10.w};
  unsigned c11[4] = {q11.x, q11.y, q11.z, q11.w};
  union { unsigned u[4]; short8 v; } A;
#pragma unroll
  for (int t = 0; t < 4; ++t) {
    float tL = fmaf(blo(c01[t]), ww1, blo(c00[t]) * ww0);
    float bL = fmaf(blo(c11[t]), ww1, blo(c10[t]) * ww0);
    float tH = fmaf(bhi(c01[t]), ww1, bhi(c00[t]) * ww0);
    float bH = fmaf(bhi(c11[t]), ww1, bhi(c10[t]) * ww0);
    A.u[t] = pk2(fmaf(bL, wh1, tL * wh0), fmaf(bH, wh1, tH * wh0));
  }
  return A.v;
}

// ---------------- pad + bf16 + CHANNEL-LAST: xp[b][hp][wp][c2] (uint = ch pair) ----------------
__global__ __launch_bounds__(256) void pad_kernel(const float* __restrict__ x,
                                                  unsigned* __restrict__ xp) {
  int i = blockIdx.x * 256 + threadIdx.x;       // (b,hp,wp,c8)
  if (i >= BB * HP * WP * 8) return;
  int c8 = i & 7;
  int t = i >> 3;
  int wp = t % WP;
  int t2 = t / WP;
  int hp = t2 % HP;
  int b = t2 / HP;
  uint4 v = make_uint4(0, 0, 0, 0);
  if (hp >= 1 && hp <= HH && wp >= 1 && wp <= WW) {
    const float* s = x + (((size_t)(b * CC + c8 * 8)) * HH + (hp - 1)) * WW + (wp - 1);
    v.x = pk2(s[0], s[HW]);
    v.y = pk2(s[2 * HW], s[3 * HW]);
    v.z = pk2(s[4 * HW], s[5 * HW]);
    v.w = pk2(s[6 * HW], s[7 * HW]);
  }
  *(uint4*)(xp + (size_t)t * 32 + c8 * 4) = v;
}

// ---------------- weight repack to bf16, K-index = kk*64+c ----------------
__global__ __launch_bounds__(256) void repackw_kernel(const float* __restrict__ wt,
                                                      const float* __restrict__ ow,
                                                      ushort* __restrict__ wb,
                                                      ushort* __restrict__ owb) {
  int i = blockIdx.x * 256 + threadIdx.x;
  if (i < OO * 576) {
    int o = i / 576, r = i % 576;
    int kk = r >> 6, c = r & 63;
    wb[i] = (ushort)f2b(wt[(o * CC + c) * 9 + kk]);
  } else if (i < OO * 576 + 32 * 576) {
    int j = i - OO * 576;
    int oc = j / 576, r = j % 576;
    int kk = r >> 6, c = r & 63;
    owb[j] = (oc < 18) ? (ushort)f2b(ow[(oc * CC + c) * 9 + kk]) : (ushort)0;
  }
}

// ---------------- fused: stage window -> offs GEMM -> deform GEMM ----------------
// block = 256 thr (4 waves) = 8x8 output tile; wave i handles tile rows {2i,2i+1} (16 px M-tile)
__global__ __launch_bounds__(256, 4) void fused_deform(const unsigned* __restrict__ xp,
                                                       const ushort* __restrict__ wb,
                                                       const ushort* __restrict__ owb,
                                                       const float* __restrict__ obias,
                                                       const float* __restrict__ bias,
                                                       float* __restrict__ out) {
  __shared__ __align__(16) unsigned win[NWIN * PXS];   // 32.4 KB
  __shared__ __align__(16) float obuf[64 * 20];        // 5.1 KB offsets transpose

  int tid = threadIdx.x;
  // XCD swizzle: each XCD owns 8 contiguous (b,ht) slabs -> window rows L2-resident
  int blk0 = blockIdx.x;
  int xcd = blk0 & 7, i = blk0 >> 3;
  int s = xcd * 8 + (i >> 4);            // slab 0..63 = b*16 + ht
  int b = s >> 4, ht = s & 15, wtile = i & 15;
  int H0 = ht * TH, W0 = wtile * TW;
  int rlo = H0 - 1, clo = W0 - 1;        // window origin in padded coords

  int wave = tid >> 6, lane = tid & 63, lm = lane & 15, lq = lane >> 4;
  const unsigned* xpb = xp + (size_t)b * (HP * WP * 32);

  // ---- stage window (coalesced uint4, zero-fill out-of-range) ----
  for (int q = tid; q < NWIN * 8; q += 256) {
    int px = q >> 3, ch = q & 7;
    int r = px / WC, c = px % WC;
    int pr = rlo + r, pc = clo + c;
    uint4 v = make_uint4(0, 0, 0, 0);
    if (pr >= 0 && pr <= HP - 1 && pc >= 0 && pc <= WP - 2)
      v = *(const uint4*)(xpb + ((size_t)pr * WP + pc) * 32 + ch * 4);
    *(uint4*)&win[px * PXS + ch * 4] = v;
  }
  __syncthreads();

  int row = 2 * wave + (lm >> 3);        // tile-local coords of pixel lm
  int col = lm & 7;
  int h = H0 + row, w = W0 + col;

  // ---- offs GEMM: 18 offset channels for this wave's 16 px (static taps, always in window) ----
  {
    f32x4 oacc[2];
    oacc[0] = (f32x4)0.0f; oacc[1] = (f32x4)0.0f;
#pragma unroll
    for (int kk = 0; kk < 9; ++kk) {
      int kh = kk / 3, kw = kk % 3;
      int widx = (row + kh + 1) * WC + (col + kw + 1);
      const unsigned* wp0 = &win[widx * PXS + lq * 4];
      union { uint4 q; short8 v; } a0, a1;
      a0.q = *(const uint4*)wp0;
      a1.q = *(const uint4*)(wp0 + 16);
#pragma unroll
      for (int nt = 0; nt < 2; ++nt) {
        short8 b0 = *(const short8*)&owb[(size_t)(nt * 16 + lm) * 576 + kk * 64 + lq * 8];
        short8 b1 = *(const short8*)&owb[(size_t)(nt * 16 + lm) * 576 + kk * 64 + 32 + lq * 8];
        oacc[nt] = __builtin_amdgcn_mfma_f32_16x16x32_bf16(a0.v, b0, oacc[nt], 0, 0, 0);
        oacc[nt] = __builtin_amdgcn_mfma_f32_16x16x32_bf16(a1.v, b1, oacc[nt], 0, 0, 0);
      }
    }
    // transpose: D(col=lm->oc, row=lq*4+r->px) -> obuf[px][tap*2+{h,w}]
#pragma unroll
    for (int nt = 0; nt < 2; ++nt) {
      int oc = nt * 16 + lm;
      if (oc < 18) {
        float bv = obias[oc];
        int idx = (oc < 9) ? (oc * 2) : ((oc - 9) * 2 + 1);
#pragma unroll
        for (int r2 = 0; r2 < 4; ++r2)
          obuf[(wave * 16 + lq * 4 + r2) * 20 + idx] = oacc[nt][r2] + bv;
      }
    }
  }
  __syncthreads();

  // each lane grabs its own pixel's 18 offsets (broadcast reads)
  float orow[20];
  {
    const float* orp = &obuf[(wave * 16 + lm) * 20];
#pragma unroll
    for (int q = 0; q < 5; ++q) *(float4*)&orow[q * 4] = *(const float4*)(orp + q * 4);
  }

  // ---- deform GEMM ----
  f32x4 acc[4];
#pragma unroll
  for (int nt = 0; nt < 4; ++nt) acc[nt] = (f32x4)0.0f;

#pragma unroll
  for (int kk = 0; kk < 9; ++kk) {
    int kh = kk / 3, kw = kk % 3;
    // padded coords, mirror reference op order; clip to [0, Hp-1]=129
    float ph = (((float)kh + orow[kk * 2]) + (float)h) + 1.0f;
    float pw = (((float)kw + orow[kk * 2 + 1]) + (float)w) + 1.0f;
    ph = fminf(fmaxf(ph, 0.0f), 129.0f);
    pw = fminf(fmaxf(pw, 0.0f), 129.0f);
    float fh0 = floorf(ph), fw0 = floorf(pw);
    int h0 = (int)fh0, w0 = (int)fw0;
    float wh1 = ph - fh0, ww1 = pw - fw0;
    float wh0 = 1.0f - wh1, ww0 = 1.0f - ww1;

    int wr0 = h0 - rlo, wc0 = w0 - clo;
    bool in = (wr0 >= 0) & (wr0 <= WR - 2) & (wc0 >= 0) & (wc0 <= WC - 2);
    short8 A0v, A1v;
    if (__all(in)) {
      // fast path: 8 x ds_read_b128 from staged window
      const unsigned* pA = &win[(wr0 * WC + wc0) * PXS + lq * 4];
      uint4 q00a = *(const uint4*)pA;
      uint4 q01a = *(const uint4*)(pA + PXS);
      uint4 q10a = *(const uint4*)(pA + WC * PXS);
      uint4 q11a = *(const uint4*)(pA + WC * PXS + PXS);
      uint4 q00b = *(const uint4*)(pA + 16);
      uint4 q01b = *(const uint4*)(pA + PXS + 16);
      uint4 q10b = *(const uint4*)(pA + WC * PXS + 16);
      uint4 q11b = *(const uint4*)(pA + WC * PXS + PXS + 16);
      A0v = lerp8(q00a, q01a, q10a, q11a, ww0, ww1, wh0, wh1);
      A1v = lerp8(q00b, q01b, q10b, q11b, ww0, ww1, wh0, wh1);
    } else {
      // fallback: global gather (wave-uniform branch; correct for any offsets)
      const unsigned* pG = xpb + ((size_t)h0 * WP + w0) * 32 + lq * 4;
      uint4 q00a = *(const uint4*)pG;
      uint4 q01a = *(const uint4*)(pG + 32);
      uint4 q10a = *(const uint4*)(pG + WP * 32);
      uint4 q11a = *(const uint4*)(pG + WP * 32 + 32);
      uint4 q00b = *(const uint4*)(pG + 16);
      uint4 q01b = *(const uint4*)(pG + 48);
      uint4 q10b = *(const uint4*)(pG + WP * 32 + 16);
      uint4 q11b = *(const uint4*)(pG + WP * 32 + 48);
      A0v = lerp8(q00a, q01a, q10a, q11a, ww0, ww1, wh0, wh1);
      A1v = lerp8(q00b, q01b, q10b, q11b, ww0, ww1, wh0, wh1);
    }
#pragma unroll
    for (int nt = 0; nt < 4; ++nt) {
      short8 b0 = *(const short8*)&wb[(size_t)(nt * 16 + lm) * 576 + kk * 64 + lq * 8];
      short8 b1 = *(const short8*)&wb[(size_t)(nt * 16 + lm) * 576 + kk * 64 + 32 + lq * 8];
      acc[nt] = __builtin_amdgcn_mfma_f32_16x16x32_bf16(A0v, b0, acc[nt], 0, 0, 0);
      acc[nt] = __builtin_amdgcn_mfma_f32_16x16x32_bf16(A1v, b1, acc[nt], 0, 0, 0);
    }
  }

  // ---- epilogue: D(col=lm->o, row=lq*4+r->px); px -> (row=px>>3, col=px&7) in tile ----
  {
    int px0 = lq * 4;
    int hrow = H0 + 2 * wave + (px0 >> 3);
    int wcol = W0 + (px0 & 7);
#pragma unroll
    for (int nt = 0; nt < 4; ++nt) {
      int o = nt * 16 + lm;
      float bv = bias[o];
      float4 st = make_float4(acc[nt][0] + bv, acc[nt][1] + bv, acc[nt][2] + bv, acc[nt][3] + bv);
      *(float4*)(out + ((size_t)(b * OO + o) * HH + hrow) * WW + wcol) = st;
    }
  }
}

extern "C" void kernel_launch(void* const* d_in, const int* in_sizes, int n_in,
                              void* d_out, int out_size, void* d_ws, size_t ws_size,
                              hipStream_t stream) {
  const float* x        = (const float*)d_in[0];
  const float* weight   = (const float*)d_in[1];
  const float* bias     = (const float*)d_in[2];
  const float* offset_w = (const float*)d_in[3];
  const float* offset_b = (const float*)d_in[4];
  float* out = (float*)d_out;

  // ws layout
  unsigned* xp  = (unsigned*)d_ws;                         // 4*131*132*32 uints = 8.85 MB
  ushort* wb  = (ushort*)(xp + (size_t)BB * HP * WP * 32); // 64*576
  ushort* owb = wb + (size_t)OO * 576;                     // 32*576

  pad_kernel<<<(BB * HP * WP * 8 + 255) / 256, 256, 0, stream>>>(x, xp);
  repackw_kernel<<<(OO * 576 + 32 * 576 + 255) / 256, 256, 0, stream>>>(weight, offset_w, wb, owb);
  fused_deform<<<1024, 256, 0, stream>>>(xp, wb, owb, offset_b, bias, out);
}